// Round 1
// 641.723 us; speedup vs baseline: 1.2103x; 1.2103x over previous
//
#include <hip/hip_runtime.h>

// T2ICrossAttentionPool on MI355X.
// Identities: w12[c,i,w] = sum_r attn*Sraw;  |wctx|^2 = a^T G a with
//   G = exact fp32 diag (register math) + off-diag G' bf16 (MFMA quadratic form).
// R10: wave = 1 cap x 1 img, TLP via launch_bounds(256,4). 568us k_main.
// R11 (this round):
//   (a) k_gram (scalar LDS loop, 1 block/CU, ~60us) -> k_gram_mfma: reuses ibfF
//       fragments as BOTH MFMA operands (A/B layouts identical in the prep
//       format), 1 wave/img, 9 MFMA per k32. Exact fp32 diag kept via direct
//       k-parallel read of fp32 imgs in the same wave.
//   (b) k_main XCD-aware block swizzle: each XCD owns a 16-wide image-pair
//       stripe (32 imgs = 3MB ibfF resident in its 4MB L2), sweeps caps
//       x-fastest. Attacks the 266MB/dispatch L2-miss refetch (fragment-load
//       latency is the MfmaUtil=20% stall).

#define NIMG 256
#define NREG 36
#define DIM 1024
#define NCAP 256
#define MAXW 60
#define WPAD 64

typedef short bf16x8 __attribute__((ext_vector_type(8)));
typedef float f32x4 __attribute__((ext_vector_type(4)));

__device__ __forceinline__ unsigned short f2bf(float f) {
  unsigned u = __float_as_uint(f);
  u += 0x7FFF + ((u >> 16) & 1);   // round-to-nearest-even
  return (unsigned short)(u >> 16);
}

// ---- prep: w1[c][w] = ||masked q row|| ----
__global__ void k_prep_w1(const float* __restrict__ caps, const int* __restrict__ cap_lens,
                          float* __restrict__ w1) {
  const int bid = blockIdx.x;          // c*64 + w
  const int c = bid >> 6;
  const int w = bid & 63;
  const int t = threadIdx.x;
  const bool valid = (w < MAXW) && (w < cap_lens[c]);
  float4 v = make_float4(0.f, 0.f, 0.f, 0.f);
  if (valid) v = *reinterpret_cast<const float4*>(caps + ((size_t)c * MAXW + w) * DIM + t * 4);
  float ss = v.x * v.x + v.y * v.y + v.z * v.z + v.w * v.w;
#pragma unroll
  for (int m = 1; m <= 32; m <<= 1) ss += __shfl_xor(ss, m);
  __shared__ float part[4];
  if ((t & 63) == 0) part[t >> 6] = ss;
  __syncthreads();
  if (t == 0) w1[bid] = sqrtf(part[0] + part[1] + part[2] + part[3]);
}

// ---- prep: caps -> A fragments, masked (rows w>=clen zero) ----
// Layout: qbfF[(((c*32 + k32)*4 + mt)*64 + lane)*8 + j]
//   = q[c][m = mt*16 + (lane&15)][k = k32*32 + (lane>>4)*8 + j]
__global__ void k_prep_caps_frag(const float* __restrict__ caps, const int* __restrict__ cap_lens,
                                 unsigned short* __restrict__ qbfF) {
  const int k32 = blockIdx.x;
  const int c = blockIdx.y;
  const int t = threadIdx.x;
  const int mt = t >> 6;
  const int lane = t & 63;
  const int m = mt * 16 + (lane & 15);
  const int k0 = k32 * 32 + (lane >> 4) * 8;
  const int clen = cap_lens[c];
  float4 v0 = make_float4(0.f, 0.f, 0.f, 0.f), v1 = v0;
  if (m < clen && m < MAXW) {
    const float* src = caps + ((size_t)c * MAXW + m) * DIM + k0;
    v0 = *reinterpret_cast<const float4*>(src);
    v1 = *reinterpret_cast<const float4*>(src + 4);
  }
  ushort4 o0, o1;
  o0.x = f2bf(v0.x); o0.y = f2bf(v0.y); o0.z = f2bf(v0.z); o0.w = f2bf(v0.w);
  o1.x = f2bf(v1.x); o1.y = f2bf(v1.y); o1.z = f2bf(v1.z); o1.w = f2bf(v1.w);
  unsigned short* dst = qbfF + ((size_t)(((c * 32 + k32) * 4 + mt) * 64 + lane)) * 8;
  *reinterpret_cast<ushort4*>(dst) = o0;
  *reinterpret_cast<ushort4*>(dst + 4) = o1;
}

// ---- prep: imgs -> B fragments (rows r>=36 zero) ----
// Layout: ibfF[(((i*32 + k32)*3 + nt)*64 + lane)*8 + j]
//   = imgs[i][r = nt*16 + (lane&15)][k = k32*32 + (lane>>4)*8 + j]
__global__ void k_prep_imgs_frag(const float* __restrict__ imgs,
                                 unsigned short* __restrict__ ibfF) {
  const int k32 = blockIdx.x;
  const int i = blockIdx.y;
  const int t = threadIdx.x;          // 0..191
  const int nt = t >> 6;
  const int lane = t & 63;
  const int r = nt * 16 + (lane & 15);
  const int k0 = k32 * 32 + (lane >> 4) * 8;
  float4 v0 = make_float4(0.f, 0.f, 0.f, 0.f), v1 = v0;
  if (r < NREG) {
    const float* src = imgs + ((size_t)i * NREG + r) * DIM + k0;
    v0 = *reinterpret_cast<const float4*>(src);
    v1 = *reinterpret_cast<const float4*>(src + 4);
  }
  ushort4 o0, o1;
  o0.x = f2bf(v0.x); o0.y = f2bf(v0.y); o0.z = f2bf(v0.z); o0.w = f2bf(v0.w);
  o1.x = f2bf(v1.x); o1.y = f2bf(v1.y); o1.z = f2bf(v1.z); o1.w = f2bf(v1.w);
  unsigned short* dst = ibfF + ((size_t)(((i * 32 + k32) * 3 + nt) * 64 + lane)) * 8;
  *reinterpret_cast<ushort4*>(dst) = o0;
  *reinterpret_cast<ushort4*>(dst + 4) = o1;
}

// ---- Gram via MFMA: one wave per image. ----
// The prep fragment layout (row = lane&15, k = (lane>>4)*8+j) is identical for
// the A and B operands of mfma_f32_16x16x32_bf16, so the SAME ibfF line feeds
// both sides: C[m][n] = sum_k X[m][k]*X[n][k] = G. Off-diag -> bf16 gbf (rows/
// cols >=36 come out 0 since padded fragment rows are 0). Diag slot of gbf = 0.
// Exact fp32 diag computed from fp32 imgs (k-parallel, 4 rows per pass).
__global__ void k_gram_mfma(const float* __restrict__ imgs,
                            const unsigned short* __restrict__ ibfF,
                            unsigned short* __restrict__ gbf,
                            float* __restrict__ gdiag) {
  const int i = blockIdx.x;
  const int lane = threadIdx.x & 63;
  const int l15 = lane & 15;
  const int quad = lane >> 4;

  // exact fp32 diag: rows r0+quad, k split across the 16 lanes of each quad
  float* dg = gdiag + (size_t)i * 48;
#pragma unroll
  for (int r0 = 0; r0 < 36; r0 += 4) {
    const int r = r0 + quad;
    const float* row = imgs + ((size_t)i * NREG + r) * DIM;
    float ss = 0.f;
#pragma unroll
    for (int p = 0; p < 16; ++p) {
      float4 v = *reinterpret_cast<const float4*>(row + p * 64 + l15 * 4);
      ss += v.x * v.x + v.y * v.y + v.z * v.z + v.w * v.w;
    }
    ss += __shfl_xor(ss, 1); ss += __shfl_xor(ss, 2);
    ss += __shfl_xor(ss, 4); ss += __shfl_xor(ss, 8);
    if (l15 == 0) dg[r] = ss;
  }
  if (lane < 12) dg[36 + lane] = 0.f;

  // off-diag via MFMA, register double-buffered fragment loads
  const unsigned short* base = ibfF + ((size_t)i * 32 * 3) * 512 + lane * 8;
  const f32x4 zero4 = {0.f, 0.f, 0.f, 0.f};
  f32x4 acc[3][3];
#pragma unroll
  for (int na = 0; na < 3; ++na)
#pragma unroll
    for (int nb = 0; nb < 3; ++nb) acc[na][nb] = zero4;
  bf16x8 f[2][3];
#pragma unroll
  for (int nt = 0; nt < 3; ++nt)
    f[0][nt] = *reinterpret_cast<const bf16x8*>(base + (size_t)nt * 512);
#pragma unroll
  for (int k32 = 0; k32 < 32; ++k32) {
    if (k32 + 1 < 32) {
      const int nb_ = (k32 + 1) & 1;
#pragma unroll
      for (int nt = 0; nt < 3; ++nt)
        f[nb_][nt] = *reinterpret_cast<const bf16x8*>(base + ((size_t)(k32 + 1) * 3 + nt) * 512);
    }
    const int b = k32 & 1;
#pragma unroll
    for (int na = 0; na < 3; ++na)
#pragma unroll
      for (int nb = 0; nb < 3; ++nb)
        acc[na][nb] = __builtin_amdgcn_mfma_f32_16x16x32_bf16(f[b][na], f[b][nb], acc[na][nb], 0, 0, 0);
  }
  unsigned short* g = gbf + (size_t)i * (48 * 64);
#pragma unroll
  for (int na = 0; na < 3; ++na)
#pragma unroll
    for (int nb = 0; nb < 3; ++nb)
#pragma unroll
      for (int rg = 0; rg < 4; ++rg) {
        const int r = na * 16 + quad * 4 + rg;   // C row
        const int c = nb * 16 + l15;             // C col
        g[r * 64 + c] = (r == c) ? (unsigned short)0 : f2bf(acc[na][nb][rg]);
      }
  // zero the K-pad cols 48..63 (16 ushorts = 2 uint4 per row)
  for (int idx = lane; idx < 96; idx += 64) {
    const int r = idx >> 1, half = idx & 1;
    *reinterpret_cast<uint4*>(g + r * 64 + 48 + half * 8) = make_uint4(0, 0, 0, 0);
  }
}

// ---- K-loop: straight-line, 2-stage register double-buffer, templated on MLIM ----
template <int MLIM>
__device__ __forceinline__ void kloopT(const unsigned short* __restrict__ aBase,
                                       const unsigned short* __restrict__ bBase,
                                       f32x4 (&acc)[4][3]) {
  bf16x8 fa[2][MLIM], fb[2][3];
  auto load = [&](int k32, int buf) __attribute__((always_inline)) {
#pragma unroll
    for (int nt = 0; nt < 3; ++nt)
      fb[buf][nt] = *reinterpret_cast<const bf16x8*>(bBase + ((size_t)k32 * 3 + nt) * 512);
#pragma unroll
    for (int mt = 0; mt < MLIM; ++mt)
      fa[buf][mt] = *reinterpret_cast<const bf16x8*>(aBase + ((size_t)k32 * 4 + mt) * 512);
  };
  auto compute = [&](int buf) __attribute__((always_inline)) {
#pragma unroll
    for (int mt = 0; mt < MLIM; ++mt)
#pragma unroll
      for (int nt = 0; nt < 3; ++nt)
        acc[mt][nt] = __builtin_amdgcn_mfma_f32_16x16x32_bf16(fa[buf][mt], fb[buf][nt], acc[mt][nt], 0, 0, 0);
  };
  load(0, 0);
#pragma unroll
  for (int k32 = 0; k32 < 32; ++k32) {
    if (k32 + 1 < 32) load(k32 + 1, (k32 + 1) & 1);
    compute(k32 & 1);
  }
}

// ---- main fused kernel ----
// Grid (I/2, C/2), block 256 = 4 waves. Wave wv: caption c0+(wv&1), image
// i0+(wv>>1) -> wave pairs share A and B fragment lines via L1.
// XCD swizzle: flat block id -> xcd = flat&7 (round-robin dispatch), each XCD
// owns bx in [xcd*16, xcd*16+16) (32 imgs, 3MB ibfF resident in its L2) and
// sweeps by (caps) with bx fastest, so cap lines are reused by 16 blocks.
__launch_bounds__(256, 4)
__global__ void k_main(const unsigned short* __restrict__ qbfF,
                       const unsigned short* __restrict__ ibfF,
                       const float* __restrict__ w1,
                       const unsigned short* __restrict__ gbf,
                       const float* __restrict__ gdiag,
                       const int* __restrict__ cap_lens,
                       float* __restrict__ out) {
  __shared__ struct {
    unsigned short attn[4][64 * 64];  // bf16 rows [w][64], swizzled; wave-private
    float w12[4][64];
    float w2d[4][64];
    float w2x[4][64];
  } lds;                               // 35840 B -> 4 blocks/CU
  const int tid = threadIdx.x;
  const int lane = tid & 63;
  const int wv = tid >> 6;
  const int l15 = lane & 15;
  const int quad = lane >> 4;
  // ---- XCD-aware swizzle (16384 blocks, %8==0 -> bijective) ----
  const int flat = blockIdx.y * (NIMG / 2) + blockIdx.x;
  const int xcd = flat & 7;
  const int idx = flat >> 3;
  const int bx = xcd * 16 + (idx & 15);
  const int by = idx >> 4;
  const int i0 = bx * 2;
  const int c = by * 2 + (wv & 1);
  const int img = i0 + (wv >> 1);
  const int clen = cap_lens[c];
  const int mlim = (clen + 15) >> 4;   // 1..4 valid A-tiles

  f32x4 acc[4][3];
  const f32x4 zero4 = {0.f, 0.f, 0.f, 0.f};
#pragma unroll
  for (int mt = 0; mt < 4; ++mt)
#pragma unroll
    for (int nt = 0; nt < 3; ++nt) acc[mt][nt] = zero4;

  const unsigned short* aBase = qbfF + ((size_t)c * 32 * 4) * 512 + lane * 8;
  const unsigned short* bBase = ibfF + ((size_t)img * 32 * 3) * 512 + lane * 8;

  switch (mlim) {
    case 1: kloopT<1>(aBase, bBase, acc); break;
    case 2: kloopT<2>(aBase, bBase, acc); break;
    case 3: kloopT<3>(aBase, bBase, acc); break;
    default: kloopT<4>(aBase, bBase, acc); break;
  }

  // ---- epilogue (all LDS below is wave-private; no cross-wave barriers) ----
  {
    uint4* ab = reinterpret_cast<uint4*>(&lds.attn[wv][0]);
    const uint4 z4 = make_uint4(0, 0, 0, 0);
    for (int j = lane; j < 512; j += 64) ab[j] = z4;   // zero incl. K-pad cols 48..63
  }

  const int lo = l15 & 7, hi = l15 >> 3;
  const float* dg = gdiag + (size_t)img * 48;
  const float d0 = dg[l15];
  const float d1 = dg[16 + l15];
  const float d2 = dg[32 + l15];

  // per-region l2 norm over w (C-layout: rows live across quads -> xor 16,32)
  float scale[3];
#pragma unroll
  for (int nt = 0; nt < 3; ++nt) {
    float p = 0.f;
#pragma unroll
    for (int mt = 0; mt < 4; ++mt)
      if (mt < mlim)
#pragma unroll
        for (int rg = 0; rg < 4; ++rg) {
          float s = acc[mt][nt][rg];
          float l = s < 0.f ? 0.1f * s : s;
          p += l * l;
        }
    p += __shfl_xor(p, 16);
    p += __shfl_xor(p, 32);
    scale[nt] = 9.0f / (sqrtf(p) + 1e-8f);   // SMOOTH folded in
  }
  const bool vr2 = (l15 < 4);   // r = 32+l15 valid only if < 36
  // softmax over r (cols across the 16 lanes of a quad -> xor 1..8), w12, diag, attn->LDS
#pragma unroll
  for (int mt = 0; mt < 4; ++mt) {
    if (mt >= mlim) continue;
#pragma unroll
    for (int rg = 0; rg < 4; ++rg) {
      const float s0 = acc[mt][0][rg];
      const float s1 = acc[mt][1][rg];
      const float s2 = acc[mt][2][rg];
      const float t0 = (s0 < 0.f ? 0.1f * s0 : s0) * scale[0];
      const float t1 = (s1 < 0.f ? 0.1f * s1 : s1) * scale[1];
      const float t2 = (s2 < 0.f ? 0.1f * s2 : s2) * scale[2];
      float mx = fmaxf(t0, t1);
      if (vr2) mx = fmaxf(mx, t2);
      mx = fmaxf(mx, __shfl_xor(mx, 1));
      mx = fmaxf(mx, __shfl_xor(mx, 2));
      mx = fmaxf(mx, __shfl_xor(mx, 4));
      mx = fmaxf(mx, __shfl_xor(mx, 8));
      const float e0 = __expf(t0 - mx);
      const float e1 = __expf(t1 - mx);
      const float e2 = vr2 ? __expf(t2 - mx) : 0.f;
      float sm = e0 + e1 + e2;
      sm += __shfl_xor(sm, 1);
      sm += __shfl_xor(sm, 2);
      sm += __shfl_xor(sm, 4);
      sm += __shfl_xor(sm, 8);
      const float inv = 1.0f / sm;
      const float a0 = e0 * inv, a1 = e1 * inv, a2 = e2 * inv;   // a2==0 when invalid
      float wp = a0 * s0 + a1 * s1 + a2 * s2;                    // w12 uses RAW s
      float dd = a0 * a0 * d0 + a1 * a1 * d1 + a2 * a2 * d2;     // exact diag term
      wp += __shfl_xor(wp, 1); wp += __shfl_xor(wp, 2);
      wp += __shfl_xor(wp, 4); wp += __shfl_xor(wp, 8);
      dd += __shfl_xor(dd, 1); dd += __shfl_xor(dd, 2);
      dd += __shfl_xor(dd, 4); dd += __shfl_xor(dd, 8);
      const int w = mt * 16 + quad * 4 + rg;
      const int w7 = w & 7;
      unsigned short* arow = &lds.attn[wv][w * 64];
      arow[(((0 + hi) ^ w7) << 3) + lo] = f2bf(a0);
      arow[(((2 + hi) ^ w7) << 3) + lo] = f2bf(a1);
      arow[(((4 + hi) ^ w7) << 3) + lo] = f2bf(a2);
      if (l15 == 0) { lds.w12[wv][w] = wp; lds.w2d[wv][w] = dd; }
    }
  }
  // Y = Attn x G' via MFMA (wave-private; in-wave lgkmcnt ordering suffices).
  // G' B-fragments straight from global (hot in L2; 1.5 MB table).
  bf16x8 gfrag[3][2];
#pragma unroll
  for (int nt = 0; nt < 3; ++nt)
#pragma unroll
    for (int ks = 0; ks < 2; ++ks)
      gfrag[nt][ks] = *reinterpret_cast<const bf16x8*>(
          gbf + ((size_t)img * 48 + nt * 16 + l15) * 64 + ((ks * 4 + quad) << 3));
#pragma unroll
  for (int mt = 0; mt < 4; ++mt) {
    if (mt >= mlim) continue;
    bf16x8 af[2];
#pragma unroll
    for (int ks = 0; ks < 2; ++ks)
      af[ks] = *reinterpret_cast<const bf16x8*>(
          &lds.attn[wv][(mt * 16 + l15) * 64 + (((ks * 4 + quad) ^ (l15 & 7)) << 3)]);
    f32x4 Y[3] = {zero4, zero4, zero4};
#pragma unroll
    for (int nt = 0; nt < 3; ++nt)
#pragma unroll
      for (int ks = 0; ks < 2; ++ks)
        Y[nt] = __builtin_amdgcn_mfma_f32_16x16x32_bf16(af[ks], gfrag[nt][ks], Y[nt], 0, 0, 0);
    // cross term: w2x[w] = sum_{r'} a[w][r'] * Y[w][r']  (Y C-layout == a C-layout)
#pragma unroll
    for (int rg = 0; rg < 4; ++rg) {
      const int w = mt * 16 + quad * 4 + rg;
      const int w7 = w & 7;
      float p = 0.f;
#pragma unroll
      for (int nt = 0; nt < 3; ++nt) {
        const unsigned short b = lds.attn[wv][w * 64 + (((nt * 2 + hi) ^ w7) << 3) + lo];
        p += __uint_as_float((unsigned)b << 16) * Y[nt][rg];
      }
      p += __shfl_xor(p, 1); p += __shfl_xor(p, 2);
      p += __shfl_xor(p, 4); p += __shfl_xor(p, 8);
      if (l15 == 0) lds.w2x[wv][w] = p;
    }
  }
  // final: lane = word
  float simv = 0.f;
  if (lane < clen) {
    const float w2sq = fmaxf(lds.w2x[wv][lane] + lds.w2d[wv][lane], 0.f);
    const float w2v = sqrtf(w2sq);
    const float w12v = lds.w12[wv][lane];
    const float w1v = w1[(size_t)c * WPAD + lane];
    simv = w12v / fmaxf(w1v * w2v, 1e-8f);
  }
  simv += __shfl_xor(simv, 1);
  simv += __shfl_xor(simv, 2);
  simv += __shfl_xor(simv, 4);
  simv += __shfl_xor(simv, 8);
  simv += __shfl_xor(simv, 16);
  simv += __shfl_xor(simv, 32);
  if (lane == 0) out[(size_t)img * NCAP + c] = simv / (float)clen;
}

extern "C" void kernel_launch(void* const* d_in, const int* in_sizes, int n_in,
                              void* d_out, int out_size, void* d_ws, size_t ws_size,
                              hipStream_t stream) {
  const float* imgs = (const float*)d_in[0];
  const float* caps = (const float*)d_in[1];
  const int* cap_lens = (const int*)d_in[3];   // img_lens (d_in[2]) unused by reference
  float* out = (float*)d_out;

  char* ws = (char*)d_ws;
  const size_t QBF_B = (size_t)NCAP * 32 * 4 * 512 * 2;      // 33,554,432
  const size_t IBF_B = (size_t)NIMG * 32 * 3 * 512 * 2;      // 25,165,824
  const size_t W1_B = (size_t)NCAP * WPAD * 4;               // 65,536
  const size_t GBF_B = (size_t)NIMG * 48 * 64 * 2;           // 1,572,864
  unsigned short* qbfF = (unsigned short*)ws;
  unsigned short* ibfF = (unsigned short*)(ws + QBF_B);
  float* w1 = (float*)(ws + QBF_B + IBF_B);
  unsigned short* gbf = (unsigned short*)(ws + QBF_B + IBF_B + W1_B);
  float* gdiag = (float*)(ws + QBF_B + IBF_B + W1_B + GBF_B);

  k_prep_w1<<<NCAP * WPAD, 256, 0, stream>>>(caps, cap_lens, w1);
  k_prep_caps_frag<<<dim3(32, NCAP), 256, 0, stream>>>(caps, cap_lens, qbfF);
  k_prep_imgs_frag<<<dim3(32, NIMG), 192, 0, stream>>>(imgs, ibfF);
  k_gram_mfma<<<NIMG, 64, 0, stream>>>(imgs, ibfF, gbf, gdiag);
  k_main<<<dim3(NIMG / 2, NCAP / 2), 256, 0, stream>>>(qbfF, ibfF, w1, gbf, gdiag, cap_lens, out);
}

// Round 2
// 597.727 us; speedup vs baseline: 1.2994x; 1.0736x over previous
//
#include <hip/hip_runtime.h>

// T2ICrossAttentionPool on MI355X.
// Identities: w12[c,i,w] = sum_r attn*Sraw;  |wctx|^2 = a^T G a with
//   G = exact fp32 diag (register math) + off-diag G' bf16 (MFMA quadratic form).
// R11: k_gram -> MFMA (prep 208->90us); XCD swizzle (FETCH 266->109MB) but
//   k_main 568->551us only => NOT HBM-bound. MfmaUtil 20, VALU 39, Occ 37.
// R12: K-loop is VMEM-latency-bound: 1-step-deep register dbuf gives ~100cy
//   cover vs ~200-450cy L2 latency. Deepen to 3 k32-steps (MLP ~11-16 loads
//   in flight), pin load-issue order with one sched_barrier(0)/iter (no
//   vmcnt drains). launch_bounds(256,3) to absorb +28 VGPR without spills.

#define NIMG 256
#define NREG 36
#define DIM 1024
#define NCAP 256
#define MAXW 60
#define WPAD 64

typedef short bf16x8 __attribute__((ext_vector_type(8)));
typedef float f32x4 __attribute__((ext_vector_type(4)));

__device__ __forceinline__ unsigned short f2bf(float f) {
  unsigned u = __float_as_uint(f);
  u += 0x7FFF + ((u >> 16) & 1);   // round-to-nearest-even
  return (unsigned short)(u >> 16);
}

// ---- prep: w1[c][w] = ||masked q row|| ----
__global__ void k_prep_w1(const float* __restrict__ caps, const int* __restrict__ cap_lens,
                          float* __restrict__ w1) {
  const int bid = blockIdx.x;          // c*64 + w
  const int c = bid >> 6;
  const int w = bid & 63;
  const int t = threadIdx.x;
  const bool valid = (w < MAXW) && (w < cap_lens[c]);
  float4 v = make_float4(0.f, 0.f, 0.f, 0.f);
  if (valid) v = *reinterpret_cast<const float4*>(caps + ((size_t)c * MAXW + w) * DIM + t * 4);
  float ss = v.x * v.x + v.y * v.y + v.z * v.z + v.w * v.w;
#pragma unroll
  for (int m = 1; m <= 32; m <<= 1) ss += __shfl_xor(ss, m);
  __shared__ float part[4];
  if ((t & 63) == 0) part[t >> 6] = ss;
  __syncthreads();
  if (t == 0) w1[bid] = sqrtf(part[0] + part[1] + part[2] + part[3]);
}

// ---- prep: caps -> A fragments, masked (rows w>=clen zero) ----
// Layout: qbfF[(((c*32 + k32)*4 + mt)*64 + lane)*8 + j]
//   = q[c][m = mt*16 + (lane&15)][k = k32*32 + (lane>>4)*8 + j]
__global__ void k_prep_caps_frag(const float* __restrict__ caps, const int* __restrict__ cap_lens,
                                 unsigned short* __restrict__ qbfF) {
  const int k32 = blockIdx.x;
  const int c = blockIdx.y;
  const int t = threadIdx.x;
  const int mt = t >> 6;
  const int lane = t & 63;
  const int m = mt * 16 + (lane & 15);
  const int k0 = k32 * 32 + (lane >> 4) * 8;
  const int clen = cap_lens[c];
  float4 v0 = make_float4(0.f, 0.f, 0.f, 0.f), v1 = v0;
  if (m < clen && m < MAXW) {
    const float* src = caps + ((size_t)c * MAXW + m) * DIM + k0;
    v0 = *reinterpret_cast<const float4*>(src);
    v1 = *reinterpret_cast<const float4*>(src + 4);
  }
  ushort4 o0, o1;
  o0.x = f2bf(v0.x); o0.y = f2bf(v0.y); o0.z = f2bf(v0.z); o0.w = f2bf(v0.w);
  o1.x = f2bf(v1.x); o1.y = f2bf(v1.y); o1.z = f2bf(v1.z); o1.w = f2bf(v1.w);
  unsigned short* dst = qbfF + ((size_t)(((c * 32 + k32) * 4 + mt) * 64 + lane)) * 8;
  *reinterpret_cast<ushort4*>(dst) = o0;
  *reinterpret_cast<ushort4*>(dst + 4) = o1;
}

// ---- prep: imgs -> B fragments (rows r>=36 zero) ----
// Layout: ibfF[(((i*32 + k32)*3 + nt)*64 + lane)*8 + j]
//   = imgs[i][r = nt*16 + (lane&15)][k = k32*32 + (lane>>4)*8 + j]
__global__ void k_prep_imgs_frag(const float* __restrict__ imgs,
                                 unsigned short* __restrict__ ibfF) {
  const int k32 = blockIdx.x;
  const int i = blockIdx.y;
  const int t = threadIdx.x;          // 0..191
  const int nt = t >> 6;
  const int lane = t & 63;
  const int r = nt * 16 + (lane & 15);
  const int k0 = k32 * 32 + (lane >> 4) * 8;
  float4 v0 = make_float4(0.f, 0.f, 0.f, 0.f), v1 = v0;
  if (r < NREG) {
    const float* src = imgs + ((size_t)i * NREG + r) * DIM + k0;
    v0 = *reinterpret_cast<const float4*>(src);
    v1 = *reinterpret_cast<const float4*>(src + 4);
  }
  ushort4 o0, o1;
  o0.x = f2bf(v0.x); o0.y = f2bf(v0.y); o0.z = f2bf(v0.z); o0.w = f2bf(v0.w);
  o1.x = f2bf(v1.x); o1.y = f2bf(v1.y); o1.z = f2bf(v1.z); o1.w = f2bf(v1.w);
  unsigned short* dst = ibfF + ((size_t)(((i * 32 + k32) * 3 + nt) * 64 + lane)) * 8;
  *reinterpret_cast<ushort4*>(dst) = o0;
  *reinterpret_cast<ushort4*>(dst + 4) = o1;
}

// ---- Gram via MFMA: one wave per image. ----
// The prep fragment layout (row = lane&15, k = (lane>>4)*8+j) is identical for
// the A and B operands of mfma_f32_16x16x32_bf16, so the SAME ibfF line feeds
// both sides: C[m][n] = sum_k X[m][k]*X[n][k] = G. Off-diag -> bf16 gbf (rows/
// cols >=36 come out 0 since padded fragment rows are 0). Diag slot of gbf = 0.
// Exact fp32 diag computed from fp32 imgs (k-parallel, 4 rows per pass).
__global__ void k_gram_mfma(const float* __restrict__ imgs,
                            const unsigned short* __restrict__ ibfF,
                            unsigned short* __restrict__ gbf,
                            float* __restrict__ gdiag) {
  const int i = blockIdx.x;
  const int lane = threadIdx.x & 63;
  const int l15 = lane & 15;
  const int quad = lane >> 4;

  // exact fp32 diag: rows r0+quad, k split across the 16 lanes of each quad
  float* dg = gdiag + (size_t)i * 48;
#pragma unroll
  for (int r0 = 0; r0 < 36; r0 += 4) {
    const int r = r0 + quad;
    const float* row = imgs + ((size_t)i * NREG + r) * DIM;
    float ss = 0.f;
#pragma unroll
    for (int p = 0; p < 16; ++p) {
      float4 v = *reinterpret_cast<const float4*>(row + p * 64 + l15 * 4);
      ss += v.x * v.x + v.y * v.y + v.z * v.z + v.w * v.w;
    }
    ss += __shfl_xor(ss, 1); ss += __shfl_xor(ss, 2);
    ss += __shfl_xor(ss, 4); ss += __shfl_xor(ss, 8);
    if (l15 == 0) dg[r] = ss;
  }
  if (lane < 12) dg[36 + lane] = 0.f;

  // off-diag via MFMA, register double-buffered fragment loads
  const unsigned short* base = ibfF + ((size_t)i * 32 * 3) * 512 + lane * 8;
  const f32x4 zero4 = {0.f, 0.f, 0.f, 0.f};
  f32x4 acc[3][3];
#pragma unroll
  for (int na = 0; na < 3; ++na)
#pragma unroll
    for (int nb = 0; nb < 3; ++nb) acc[na][nb] = zero4;
  bf16x8 f[2][3];
#pragma unroll
  for (int nt = 0; nt < 3; ++nt)
    f[0][nt] = *reinterpret_cast<const bf16x8*>(base + (size_t)nt * 512);
#pragma unroll
  for (int k32 = 0; k32 < 32; ++k32) {
    if (k32 + 1 < 32) {
      const int nb_ = (k32 + 1) & 1;
#pragma unroll
      for (int nt = 0; nt < 3; ++nt)
        f[nb_][nt] = *reinterpret_cast<const bf16x8*>(base + ((size_t)(k32 + 1) * 3 + nt) * 512);
    }
    const int b = k32 & 1;
#pragma unroll
    for (int na = 0; na < 3; ++na)
#pragma unroll
      for (int nb = 0; nb < 3; ++nb)
        acc[na][nb] = __builtin_amdgcn_mfma_f32_16x16x32_bf16(f[b][na], f[b][nb], acc[na][nb], 0, 0, 0);
  }
  unsigned short* g = gbf + (size_t)i * (48 * 64);
#pragma unroll
  for (int na = 0; na < 3; ++na)
#pragma unroll
    for (int nb = 0; nb < 3; ++nb)
#pragma unroll
      for (int rg = 0; rg < 4; ++rg) {
        const int r = na * 16 + quad * 4 + rg;   // C row
        const int c = nb * 16 + l15;             // C col
        g[r * 64 + c] = (r == c) ? (unsigned short)0 : f2bf(acc[na][nb][rg]);
      }
  // zero the K-pad cols 48..63 (16 ushorts = 2 uint4 per row)
  for (int idx = lane; idx < 96; idx += 64) {
    const int r = idx >> 1, half = idx & 1;
    *reinterpret_cast<uint4*>(g + r * 64 + 48 + half * 8) = make_uint4(0, 0, 0, 0);
  }
}

// ---- K-loop: straight-line, 3-stage register pipeline, templated on MLIM ----
// Depth-3: loads for step k+2 issue while step k computes -> ~2 iterations
// (~2*(MLIM+3) loads) in flight to cover L2-hit latency. One sched_barrier(0)
// per iteration pins the issue point (prevents the R9 collapse); the waits
// themselves are the compiler's own exact vmcnt insertions on the reg deps.
template <int MLIM>
__device__ __forceinline__ void kloopT(const unsigned short* __restrict__ aBase,
                                       const unsigned short* __restrict__ bBase,
                                       f32x4 (&acc)[4][3]) {
  bf16x8 fa[3][MLIM], fb[3][3];
  auto load = [&](int k32, int buf) __attribute__((always_inline)) {
#pragma unroll
    for (int nt = 0; nt < 3; ++nt)
      fb[buf][nt] = *reinterpret_cast<const bf16x8*>(bBase + ((size_t)k32 * 3 + nt) * 512);
#pragma unroll
    for (int mt = 0; mt < MLIM; ++mt)
      fa[buf][mt] = *reinterpret_cast<const bf16x8*>(aBase + ((size_t)k32 * 4 + mt) * 512);
  };
  auto compute = [&](int buf) __attribute__((always_inline)) {
#pragma unroll
    for (int mt = 0; mt < MLIM; ++mt)
#pragma unroll
      for (int nt = 0; nt < 3; ++nt)
        acc[mt][nt] = __builtin_amdgcn_mfma_f32_16x16x32_bf16(fa[buf][mt], fb[buf][nt], acc[mt][nt], 0, 0, 0);
  };
  load(0, 0);
  load(1, 1);
#pragma unroll
  for (int k32 = 0; k32 < 32; ++k32) {
    if (k32 + 2 < 32) load(k32 + 2, (k32 + 2) % 3);
    __builtin_amdgcn_sched_barrier(0);   // pin: prefetch issued above, MFMAs stay below
    compute(k32 % 3);
  }
}

// ---- main fused kernel ----
// Grid (I/2, C/2), block 256 = 4 waves. Wave wv: caption c0+(wv&1), image
// i0+(wv>>1) -> wave pairs share A and B fragment lines via L1.
// XCD swizzle: flat block id -> xcd = flat&7 (round-robin dispatch), each XCD
// owns bx in [xcd*16, xcd*16+16) (32 imgs, 3MB ibfF resident in its L2) and
// sweeps by (caps) with bx fastest, so cap lines are reused by 16 blocks.
__launch_bounds__(256, 3)
__global__ void k_main(const unsigned short* __restrict__ qbfF,
                       const unsigned short* __restrict__ ibfF,
                       const float* __restrict__ w1,
                       const unsigned short* __restrict__ gbf,
                       const float* __restrict__ gdiag,
                       const int* __restrict__ cap_lens,
                       float* __restrict__ out) {
  __shared__ struct {
    unsigned short attn[4][64 * 64];  // bf16 rows [w][64], swizzled; wave-private
    float w12[4][64];
    float w2d[4][64];
    float w2x[4][64];
  } lds;                               // 35840 B -> 4 blocks/CU
  const int tid = threadIdx.x;
  const int lane = tid & 63;
  const int wv = tid >> 6;
  const int l15 = lane & 15;
  const int quad = lane >> 4;
  // ---- XCD-aware swizzle (16384 blocks, %8==0 -> bijective) ----
  const int flat = blockIdx.y * (NIMG / 2) + blockIdx.x;
  const int xcd = flat & 7;
  const int idx = flat >> 3;
  const int bx = xcd * 16 + (idx & 15);
  const int by = idx >> 4;
  const int i0 = bx * 2;
  const int c = by * 2 + (wv & 1);
  const int img = i0 + (wv >> 1);
  const int clen = cap_lens[c];
  const int mlim = (clen + 15) >> 4;   // 1..4 valid A-tiles

  f32x4 acc[4][3];
  const f32x4 zero4 = {0.f, 0.f, 0.f, 0.f};
#pragma unroll
  for (int mt = 0; mt < 4; ++mt)
#pragma unroll
    for (int nt = 0; nt < 3; ++nt) acc[mt][nt] = zero4;

  const unsigned short* aBase = qbfF + ((size_t)c * 32 * 4) * 512 + lane * 8;
  const unsigned short* bBase = ibfF + ((size_t)img * 32 * 3) * 512 + lane * 8;

  switch (mlim) {
    case 1: kloopT<1>(aBase, bBase, acc); break;
    case 2: kloopT<2>(aBase, bBase, acc); break;
    case 3: kloopT<3>(aBase, bBase, acc); break;
    default: kloopT<4>(aBase, bBase, acc); break;
  }

  // ---- epilogue (all LDS below is wave-private; no cross-wave barriers) ----
  {
    uint4* ab = reinterpret_cast<uint4*>(&lds.attn[wv][0]);
    const uint4 z4 = make_uint4(0, 0, 0, 0);
    for (int j = lane; j < 512; j += 64) ab[j] = z4;   // zero incl. K-pad cols 48..63
  }

  const int lo = l15 & 7, hi = l15 >> 3;
  const float* dg = gdiag + (size_t)img * 48;
  const float d0 = dg[l15];
  const float d1 = dg[16 + l15];
  const float d2 = dg[32 + l15];

  // per-region l2 norm over w (C-layout: rows live across quads -> xor 16,32)
  float scale[3];
#pragma unroll
  for (int nt = 0; nt < 3; ++nt) {
    float p = 0.f;
#pragma unroll
    for (int mt = 0; mt < 4; ++mt)
      if (mt < mlim)
#pragma unroll
        for (int rg = 0; rg < 4; ++rg) {
          float s = acc[mt][nt][rg];
          float l = s < 0.f ? 0.1f * s : s;
          p += l * l;
        }
    p += __shfl_xor(p, 16);
    p += __shfl_xor(p, 32);
    scale[nt] = 9.0f / (sqrtf(p) + 1e-8f);   // SMOOTH folded in
  }
  const bool vr2 = (l15 < 4);   // r = 32+l15 valid only if < 36
  // softmax over r (cols across the 16 lanes of a quad -> xor 1..8), w12, diag, attn->LDS
#pragma unroll
  for (int mt = 0; mt < 4; ++mt) {
    if (mt >= mlim) continue;
#pragma unroll
    for (int rg = 0; rg < 4; ++rg) {
      const float s0 = acc[mt][0][rg];
      const float s1 = acc[mt][1][rg];
      const float s2 = acc[mt][2][rg];
      const float t0 = (s0 < 0.f ? 0.1f * s0 : s0) * scale[0];
      const float t1 = (s1 < 0.f ? 0.1f * s1 : s1) * scale[1];
      const float t2 = (s2 < 0.f ? 0.1f * s2 : s2) * scale[2];
      float mx = fmaxf(t0, t1);
      if (vr2) mx = fmaxf(mx, t2);
      mx = fmaxf(mx, __shfl_xor(mx, 1));
      mx = fmaxf(mx, __shfl_xor(mx, 2));
      mx = fmaxf(mx, __shfl_xor(mx, 4));
      mx = fmaxf(mx, __shfl_xor(mx, 8));
      const float e0 = __expf(t0 - mx);
      const float e1 = __expf(t1 - mx);
      const float e2 = vr2 ? __expf(t2 - mx) : 0.f;
      float sm = e0 + e1 + e2;
      sm += __shfl_xor(sm, 1);
      sm += __shfl_xor(sm, 2);
      sm += __shfl_xor(sm, 4);
      sm += __shfl_xor(sm, 8);
      const float inv = 1.0f / sm;
      const float a0 = e0 * inv, a1 = e1 * inv, a2 = e2 * inv;   // a2==0 when invalid
      float wp = a0 * s0 + a1 * s1 + a2 * s2;                    // w12 uses RAW s
      float dd = a0 * a0 * d0 + a1 * a1 * d1 + a2 * a2 * d2;     // exact diag term
      wp += __shfl_xor(wp, 1); wp += __shfl_xor(wp, 2);
      wp += __shfl_xor(wp, 4); wp += __shfl_xor(wp, 8);
      dd += __shfl_xor(dd, 1); dd += __shfl_xor(dd, 2);
      dd += __shfl_xor(dd, 4); dd += __shfl_xor(dd, 8);
      const int w = mt * 16 + quad * 4 + rg;
      const int w7 = w & 7;
      unsigned short* arow = &lds.attn[wv][w * 64];
      arow[(((0 + hi) ^ w7) << 3) + lo] = f2bf(a0);
      arow[(((2 + hi) ^ w7) << 3) + lo] = f2bf(a1);
      arow[(((4 + hi) ^ w7) << 3) + lo] = f2bf(a2);
      if (l15 == 0) { lds.w12[wv][w] = wp; lds.w2d[wv][w] = dd; }
    }
  }
  // Y = Attn x G' via MFMA (wave-private; in-wave lgkmcnt ordering suffices).
  // G' B-fragments straight from global (hot in L2; 1.5 MB table).
  bf16x8 gfrag[3][2];
#pragma unroll
  for (int nt = 0; nt < 3; ++nt)
#pragma unroll
    for (int ks = 0; ks < 2; ++ks)
      gfrag[nt][ks] = *reinterpret_cast<const bf16x8*>(
          gbf + ((size_t)img * 48 + nt * 16 + l15) * 64 + ((ks * 4 + quad) << 3));
#pragma unroll
  for (int mt = 0; mt < 4; ++mt) {
    if (mt >= mlim) continue;
    bf16x8 af[2];
#pragma unroll
    for (int ks = 0; ks < 2; ++ks)
      af[ks] = *reinterpret_cast<const bf16x8*>(
          &lds.attn[wv][(mt * 16 + l15) * 64 + (((ks * 4 + quad) ^ (l15 & 7)) << 3)]);
    f32x4 Y[3] = {zero4, zero4, zero4};
#pragma unroll
    for (int nt = 0; nt < 3; ++nt)
#pragma unroll
      for (int ks = 0; ks < 2; ++ks)
        Y[nt] = __builtin_amdgcn_mfma_f32_16x16x32_bf16(af[ks], gfrag[nt][ks], Y[nt], 0, 0, 0);
    // cross term: w2x[w] = sum_{r'} a[w][r'] * Y[w][r']  (Y C-layout == a C-layout)
#pragma unroll
    for (int rg = 0; rg < 4; ++rg) {
      const int w = mt * 16 + quad * 4 + rg;
      const int w7 = w & 7;
      float p = 0.f;
#pragma unroll
      for (int nt = 0; nt < 3; ++nt) {
        const unsigned short b = lds.attn[wv][w * 64 + (((nt * 2 + hi) ^ w7) << 3) + lo];
        p += __uint_as_float((unsigned)b << 16) * Y[nt][rg];
      }
      p += __shfl_xor(p, 1); p += __shfl_xor(p, 2);
      p += __shfl_xor(p, 4); p += __shfl_xor(p, 8);
      if (l15 == 0) lds.w2x[wv][w] = p;
    }
  }
  // final: lane = word
  float simv = 0.f;
  if (lane < clen) {
    const float w2sq = fmaxf(lds.w2x[wv][lane] + lds.w2d[wv][lane], 0.f);
    const float w2v = sqrtf(w2sq);
    const float w12v = lds.w12[wv][lane];
    const float w1v = w1[(size_t)c * WPAD + lane];
    simv = w12v / fmaxf(w1v * w2v, 1e-8f);
  }
  simv += __shfl_xor(simv, 1);
  simv += __shfl_xor(simv, 2);
  simv += __shfl_xor(simv, 4);
  simv += __shfl_xor(simv, 8);
  simv += __shfl_xor(simv, 16);
  simv += __shfl_xor(simv, 32);
  if (lane == 0) out[(size_t)img * NCAP + c] = simv / (float)clen;
}

extern "C" void kernel_launch(void* const* d_in, const int* in_sizes, int n_in,
                              void* d_out, int out_size, void* d_ws, size_t ws_size,
                              hipStream_t stream) {
  const float* imgs = (const float*)d_in[0];
  const float* caps = (const float*)d_in[1];
  const int* cap_lens = (const int*)d_in[3];   // img_lens (d_in[2]) unused by reference
  float* out = (float*)d_out;

  char* ws = (char*)d_ws;
  const size_t QBF_B = (size_t)NCAP * 32 * 4 * 512 * 2;      // 33,554,432
  const size_t IBF_B = (size_t)NIMG * 32 * 3 * 512 * 2;      // 25,165,824
  const size_t W1_B = (size_t)NCAP * WPAD * 4;               // 65,536
  const size_t GBF_B = (size_t)NIMG * 48 * 64 * 2;           // 1,572,864
  unsigned short* qbfF = (unsigned short*)ws;
  unsigned short* ibfF = (unsigned short*)(ws + QBF_B);
  float* w1 = (float*)(ws + QBF_B + IBF_B);
  unsigned short* gbf = (unsigned short*)(ws + QBF_B + IBF_B + W1_B);
  float* gdiag = (float*)(ws + QBF_B + IBF_B + W1_B + GBF_B);

  k_prep_w1<<<NCAP * WPAD, 256, 0, stream>>>(caps, cap_lens, w1);
  k_prep_caps_frag<<<dim3(32, NCAP), 256, 0, stream>>>(caps, cap_lens, qbfF);
  k_prep_imgs_frag<<<dim3(32, NIMG), 192, 0, stream>>>(imgs, ibfF);
  k_gram_mfma<<<NIMG, 64, 0, stream>>>(imgs, ibfF, gbf, gdiag);
  k_main<<<dim3(NIMG / 2, NCAP / 2), 256, 0, stream>>>(qbfF, ibfF, w1, gbf, gdiag, cap_lens, out);
}

// Round 3
// 522.587 us; speedup vs baseline: 1.4862x; 1.1438x over previous
//
#include <hip/hip_runtime.h>

// T2ICrossAttentionPool on MI355X.
// Identities: w12[c,i,w] = sum_r attn*Sraw;  |wctx|^2 = a^T G a with
//   G = exact fp32 diag (register math) + off-diag G' bf16 (MFMA quadratic form).
// R11: k_gram -> MFMA (prep 208->90us); XCD swizzle (FETCH 266->109MB).
// R12: depth-3 K-loop pipeline (+7%, occupancy 37->30 from +regs).
// R13: TRANSPOSED epilogue. Swap MFMA operands (A=img frags, B=cap frags;
//   frag layouts identical) so C: col=w(lane), row=r(regs). Softmax/w12/dd
//   reductions become in-reg + xor16,32 (2 shfl) instead of 4-shfl
//   butterflies; max-sub deleted (|t|<=9 provable); w2x via swapped Y-MFMA
//   (A=G,B=attn) lands Yt in the attn register layout -> 12 FMA + 2 shfl.
//   DS-ops/wave ~270 -> ~90. Norm moves to lane dim (48 ILP shfl) - accepted.

#define NIMG 256
#define NREG 36
#define DIM 1024
#define NCAP 256
#define MAXW 60
#define WPAD 64

typedef short bf16x8 __attribute__((ext_vector_type(8)));
typedef float f32x4 __attribute__((ext_vector_type(4)));

__device__ __forceinline__ unsigned short f2bf(float f) {
  unsigned u = __float_as_uint(f);
  u += 0x7FFF + ((u >> 16) & 1);   // round-to-nearest-even
  return (unsigned short)(u >> 16);
}

// ---- prep: w1[c][w] = ||masked q row|| ----
__global__ void k_prep_w1(const float* __restrict__ caps, const int* __restrict__ cap_lens,
                          float* __restrict__ w1) {
  const int bid = blockIdx.x;          // c*64 + w
  const int c = bid >> 6;
  const int w = bid & 63;
  const int t = threadIdx.x;
  const bool valid = (w < MAXW) && (w < cap_lens[c]);
  float4 v = make_float4(0.f, 0.f, 0.f, 0.f);
  if (valid) v = *reinterpret_cast<const float4*>(caps + ((size_t)c * MAXW + w) * DIM + t * 4);
  float ss = v.x * v.x + v.y * v.y + v.z * v.z + v.w * v.w;
#pragma unroll
  for (int m = 1; m <= 32; m <<= 1) ss += __shfl_xor(ss, m);
  __shared__ float part[4];
  if ((t & 63) == 0) part[t >> 6] = ss;
  __syncthreads();
  if (t == 0) w1[bid] = sqrtf(part[0] + part[1] + part[2] + part[3]);
}

// ---- prep: caps -> fragments, masked (rows w>=clen zero) ----
// Layout: qbfF[(((c*32 + k32)*4 + mt)*64 + lane)*8 + j]
//   = q[c][m = mt*16 + (lane&15)][k = k32*32 + (lane>>4)*8 + j]
__global__ void k_prep_caps_frag(const float* __restrict__ caps, const int* __restrict__ cap_lens,
                                 unsigned short* __restrict__ qbfF) {
  const int k32 = blockIdx.x;
  const int c = blockIdx.y;
  const int t = threadIdx.x;
  const int mt = t >> 6;
  const int lane = t & 63;
  const int m = mt * 16 + (lane & 15);
  const int k0 = k32 * 32 + (lane >> 4) * 8;
  const int clen = cap_lens[c];
  float4 v0 = make_float4(0.f, 0.f, 0.f, 0.f), v1 = v0;
  if (m < clen && m < MAXW) {
    const float* src = caps + ((size_t)c * MAXW + m) * DIM + k0;
    v0 = *reinterpret_cast<const float4*>(src);
    v1 = *reinterpret_cast<const float4*>(src + 4);
  }
  ushort4 o0, o1;
  o0.x = f2bf(v0.x); o0.y = f2bf(v0.y); o0.z = f2bf(v0.z); o0.w = f2bf(v0.w);
  o1.x = f2bf(v1.x); o1.y = f2bf(v1.y); o1.z = f2bf(v1.z); o1.w = f2bf(v1.w);
  unsigned short* dst = qbfF + ((size_t)(((c * 32 + k32) * 4 + mt) * 64 + lane)) * 8;
  *reinterpret_cast<ushort4*>(dst) = o0;
  *reinterpret_cast<ushort4*>(dst + 4) = o1;
}

// ---- prep: imgs -> fragments (rows r>=36 zero) ----
// Layout: ibfF[(((i*32 + k32)*3 + nt)*64 + lane)*8 + j]
//   = imgs[i][r = nt*16 + (lane&15)][k = k32*32 + (lane>>4)*8 + j]
__global__ void k_prep_imgs_frag(const float* __restrict__ imgs,
                                 unsigned short* __restrict__ ibfF) {
  const int k32 = blockIdx.x;
  const int i = blockIdx.y;
  const int t = threadIdx.x;          // 0..191
  const int nt = t >> 6;
  const int lane = t & 63;
  const int r = nt * 16 + (lane & 15);
  const int k0 = k32 * 32 + (lane >> 4) * 8;
  float4 v0 = make_float4(0.f, 0.f, 0.f, 0.f), v1 = v0;
  if (r < NREG) {
    const float* src = imgs + ((size_t)i * NREG + r) * DIM + k0;
    v0 = *reinterpret_cast<const float4*>(src);
    v1 = *reinterpret_cast<const float4*>(src + 4);
  }
  ushort4 o0, o1;
  o0.x = f2bf(v0.x); o0.y = f2bf(v0.y); o0.z = f2bf(v0.z); o0.w = f2bf(v0.w);
  o1.x = f2bf(v1.x); o1.y = f2bf(v1.y); o1.z = f2bf(v1.z); o1.w = f2bf(v1.w);
  unsigned short* dst = ibfF + ((size_t)(((i * 32 + k32) * 3 + nt) * 64 + lane)) * 8;
  *reinterpret_cast<ushort4*>(dst) = o0;
  *reinterpret_cast<ushort4*>(dst + 4) = o1;
}

// ---- Gram via MFMA: one wave per image (same ibfF line feeds both operands) ----
__global__ void k_gram_mfma(const float* __restrict__ imgs,
                            const unsigned short* __restrict__ ibfF,
                            unsigned short* __restrict__ gbf,
                            float* __restrict__ gdiag) {
  const int i = blockIdx.x;
  const int lane = threadIdx.x & 63;
  const int l15 = lane & 15;
  const int quad = lane >> 4;

  // exact fp32 diag: rows r0+quad, k split across the 16 lanes of each quad
  float* dg = gdiag + (size_t)i * 48;
#pragma unroll
  for (int r0 = 0; r0 < 36; r0 += 4) {
    const int r = r0 + quad;
    const float* row = imgs + ((size_t)i * NREG + r) * DIM;
    float ss = 0.f;
#pragma unroll
    for (int p = 0; p < 16; ++p) {
      float4 v = *reinterpret_cast<const float4*>(row + p * 64 + l15 * 4);
      ss += v.x * v.x + v.y * v.y + v.z * v.z + v.w * v.w;
    }
    ss += __shfl_xor(ss, 1); ss += __shfl_xor(ss, 2);
    ss += __shfl_xor(ss, 4); ss += __shfl_xor(ss, 8);
    if (l15 == 0) dg[r] = ss;
  }
  if (lane < 12) dg[36 + lane] = 0.f;

  const unsigned short* base = ibfF + ((size_t)i * 32 * 3) * 512 + lane * 8;
  const f32x4 zero4 = {0.f, 0.f, 0.f, 0.f};
  f32x4 acc[3][3];
#pragma unroll
  for (int na = 0; na < 3; ++na)
#pragma unroll
    for (int nb = 0; nb < 3; ++nb) acc[na][nb] = zero4;
  bf16x8 f[2][3];
#pragma unroll
  for (int nt = 0; nt < 3; ++nt)
    f[0][nt] = *reinterpret_cast<const bf16x8*>(base + (size_t)nt * 512);
#pragma unroll
  for (int k32 = 0; k32 < 32; ++k32) {
    if (k32 + 1 < 32) {
      const int nb_ = (k32 + 1) & 1;
#pragma unroll
      for (int nt = 0; nt < 3; ++nt)
        f[nb_][nt] = *reinterpret_cast<const bf16x8*>(base + ((size_t)(k32 + 1) * 3 + nt) * 512);
    }
    const int b = k32 & 1;
#pragma unroll
    for (int na = 0; na < 3; ++na)
#pragma unroll
      for (int nb = 0; nb < 3; ++nb)
        acc[na][nb] = __builtin_amdgcn_mfma_f32_16x16x32_bf16(f[b][na], f[b][nb], acc[na][nb], 0, 0, 0);
  }
  unsigned short* g = gbf + (size_t)i * (48 * 64);
#pragma unroll
  for (int na = 0; na < 3; ++na)
#pragma unroll
    for (int nb = 0; nb < 3; ++nb)
#pragma unroll
      for (int rg = 0; rg < 4; ++rg) {
        const int r = na * 16 + quad * 4 + rg;   // C row
        const int c = nb * 16 + l15;             // C col
        g[r * 64 + c] = (r == c) ? (unsigned short)0 : f2bf(acc[na][nb][rg]);
      }
  // zero the K-pad cols 48..63 (16 ushorts = 2 uint4 per row)
  for (int idx = lane; idx < 96; idx += 64) {
    const int r = idx >> 1, half = idx & 1;
    *reinterpret_cast<uint4*>(g + r * 64 + 48 + half * 8) = make_uint4(0, 0, 0, 0);
  }
}

// ---- K-loop: S^T = imgs x caps^T. A-op = ibfF (3 nt tiles), B-op = qbfF
// (MLIM mt tiles); acc[nt][mt]: col = w (l15), row = r (quad*4+rg).
// Depth-3 register pipeline, sched_barrier(0) pins prefetch issue point.
template <int MLIM>
__device__ __forceinline__ void kloopT(const unsigned short* __restrict__ aBase,  // caps
                                       const unsigned short* __restrict__ bBase,  // imgs
                                       f32x4 (&acc)[3][4]) {
  bf16x8 fa[3][MLIM], fb[3][3];
  auto load = [&](int k32, int buf) __attribute__((always_inline)) {
#pragma unroll
    for (int nt = 0; nt < 3; ++nt)
      fb[buf][nt] = *reinterpret_cast<const bf16x8*>(bBase + ((size_t)k32 * 3 + nt) * 512);
#pragma unroll
    for (int mt = 0; mt < MLIM; ++mt)
      fa[buf][mt] = *reinterpret_cast<const bf16x8*>(aBase + ((size_t)k32 * 4 + mt) * 512);
  };
  auto compute = [&](int buf) __attribute__((always_inline)) {
#pragma unroll
    for (int mt = 0; mt < MLIM; ++mt)
#pragma unroll
      for (int nt = 0; nt < 3; ++nt)
        acc[nt][mt] = __builtin_amdgcn_mfma_f32_16x16x32_bf16(fb[buf][nt], fa[buf][mt], acc[nt][mt], 0, 0, 0);
  };
  load(0, 0);
  load(1, 1);
#pragma unroll
  for (int k32 = 0; k32 < 32; ++k32) {
    if (k32 + 2 < 32) load(k32 + 2, (k32 + 2) % 3);
    __builtin_amdgcn_sched_barrier(0);   // pin: prefetch issued above, MFMAs stay below
    compute(k32 % 3);
  }
}

// ---- main fused kernel ----
// Grid (I/2, C/2), block 256 = 4 waves. Wave wv: caption c0+(wv&1), image
// i0+(wv>>1). XCD swizzle: each XCD owns a 16-wide image-pair stripe.
__launch_bounds__(256, 3)
__global__ void k_main(const unsigned short* __restrict__ qbfF,
                       const unsigned short* __restrict__ ibfF,
                       const float* __restrict__ w1,
                       const unsigned short* __restrict__ gbf,
                       const float* __restrict__ gdiag,
                       const int* __restrict__ cap_lens,
                       float* __restrict__ out) {
  __shared__ struct {
    unsigned short attn[4][64 * 64];  // bf16 [w][r], r-groups XOR-swizzled by w&7
    float w12[4][64];
    float w2d[4][64];
    float w2x[4][64];
  } lds;                               // 35840 B
  const int tid = threadIdx.x;
  const int lane = tid & 63;
  const int wv = tid >> 6;
  const int l15 = lane & 15;
  const int quad = lane >> 4;
  // ---- XCD-aware swizzle (16384 blocks, %8==0 -> bijective) ----
  const int flat = blockIdx.y * (NIMG / 2) + blockIdx.x;
  const int xcd = flat & 7;
  const int idx = flat >> 3;
  const int bx = xcd * 16 + (idx & 15);
  const int by = idx >> 4;
  const int i0 = bx * 2;
  const int c = by * 2 + (wv & 1);
  const int img = i0 + (wv >> 1);
  const int clen = cap_lens[c];
  const int mlim = (clen + 15) >> 4;   // 1..4 valid w-tiles

  f32x4 acc[3][4];
  const f32x4 zero4 = {0.f, 0.f, 0.f, 0.f};
#pragma unroll
  for (int nt = 0; nt < 3; ++nt)
#pragma unroll
    for (int mt = 0; mt < 4; ++mt) acc[nt][mt] = zero4;

  const unsigned short* aBase = qbfF + ((size_t)c * 32 * 4) * 512 + lane * 8;
  const unsigned short* bBase = ibfF + ((size_t)img * 32 * 3) * 512 + lane * 8;

  switch (mlim) {
    case 1: kloopT<1>(aBase, bBase, acc); break;
    case 2: kloopT<2>(aBase, bBase, acc); break;
    case 3: kloopT<3>(aBase, bBase, acc); break;
    default: kloopT<4>(aBase, bBase, acc); break;
  }

  // ---- epilogue (wave-private LDS; in-wave lgkmcnt ordering suffices) ----
  {
    uint4* ab = reinterpret_cast<uint4*>(&lds.attn[wv][0]);
    const uint4 z4 = make_uint4(0, 0, 0, 0);
    for (int j = lane; j < 512; j += 64) ab[j] = z4;   // zero all (incl. pad groups)
  }

  // exact diag per register row r = nt*16 + quad*4 + rg
  const float* dg = gdiag + (size_t)img * 48;
  float dv[3][4];
#pragma unroll
  for (int nt = 0; nt < 3; ++nt)
#pragma unroll
    for (int rg = 0; rg < 4; ++rg)
      dv[nt][rg] = dg[nt * 16 + quad * 4 + rg];

  // pass 1: per-region l2 norm over w -> scale (w = lane dim: in-reg over mt,
  // then xor1..8; 12 independent butterflies, ILP-overlapped)
  float scale[3][4];
#pragma unroll
  for (int nt = 0; nt < 3; ++nt)
#pragma unroll
    for (int rg = 0; rg < 4; ++rg) {
      float p = 0.f;
#pragma unroll
      for (int mt = 0; mt < 4; ++mt)
        if (mt < mlim) {
          const float s = acc[nt][mt][rg];
          const float l = s < 0.f ? 0.1f * s : s;
          p += l * l;
        }
      p += __shfl_xor(p, 1); p += __shfl_xor(p, 2);
      p += __shfl_xor(p, 4); p += __shfl_xor(p, 8);
      scale[nt][rg] = 9.0f / (sqrtf(p) + 1e-8f);   // SMOOTH folded in
    }

  // pass 2: softmax over r per w-column. |t| <= 9 (norm >= |leak| elementwise)
  // -> no max subtraction needed. Invalid r (>=36): nt==2 && quad!=0 -> e=0.
  float a_all[4][3][4];   // un-normalized e; inv folded in at use sites
  float inv4[4];
#pragma unroll
  for (int mt = 0; mt < 4; ++mt) {
    if (mt >= mlim) continue;
    float sm = 0.f, wp = 0.f, dd = 0.f;
#pragma unroll
    for (int nt = 0; nt < 3; ++nt) {
      const bool rvalid = (nt < 2) || (quad == 0);
#pragma unroll
      for (int rg = 0; rg < 4; ++rg) {
        const float s = acc[nt][mt][rg];
        const float l = s < 0.f ? 0.1f * s : s;
        const float ee = rvalid ? __expf(l * scale[nt][rg]) : 0.f;
        a_all[mt][nt][rg] = ee;
        sm += ee;
        wp += ee * s;                       // w12 uses RAW s
        dd += ee * ee * dv[nt][rg];         // exact diag term
      }
    }
    sm += __shfl_xor(sm, 16); sm += __shfl_xor(sm, 32);
    wp += __shfl_xor(wp, 16); wp += __shfl_xor(wp, 32);
    dd += __shfl_xor(dd, 16); dd += __shfl_xor(dd, 32);
    const float inv = 1.0f / sm;
    inv4[mt] = inv;
    const int w = mt * 16 + l15;
    const int key = l15 & 7;
    unsigned short* arow = &lds.attn[wv][w * 64];
#pragma unroll
    for (int nt = 0; nt < 3; ++nt)
#pragma unroll
      for (int rg = 0; rg < 4; ++rg) {
        const int r = nt * 16 + quad * 4 + rg;
        arow[(((r >> 3) ^ key) << 3) + (r & 7)] = f2bf(a_all[mt][nt][rg] * inv);
      }
    if (quad == 0) { lds.w12[wv][w] = wp * inv; lds.w2d[wv][w] = dd * inv * inv; }
  }

  // Yt = G x Attn^T via MFMA (A=G rows r, B=attn cols w) -> Yt[nt][rg] at lane
  // (l15,quad) = Y[r = nt*16+quad*4+rg][w = mt*16+l15]: SAME layout as a_all.
  bf16x8 gfrag[3][2];
#pragma unroll
  for (int nt = 0; nt < 3; ++nt)
#pragma unroll
    for (int ks = 0; ks < 2; ++ks)
      gfrag[nt][ks] = *reinterpret_cast<const bf16x8*>(
          gbf + ((size_t)img * 48 + nt * 16 + l15) * 64 + ((ks * 4 + quad) << 3));
#pragma unroll
  for (int mt = 0; mt < 4; ++mt) {
    if (mt >= mlim) continue;
    bf16x8 af[2];
#pragma unroll
    for (int ks = 0; ks < 2; ++ks)
      af[ks] = *reinterpret_cast<const bf16x8*>(
          &lds.attn[wv][(mt * 16 + l15) * 64 + (((ks * 4 + quad) ^ (l15 & 7)) << 3)]);
    f32x4 Yt[3] = {zero4, zero4, zero4};
#pragma unroll
    for (int nt = 0; nt < 3; ++nt)
#pragma unroll
      for (int ks = 0; ks < 2; ++ks)
        Yt[nt] = __builtin_amdgcn_mfma_f32_16x16x32_bf16(gfrag[nt][ks], af[ks], Yt[nt], 0, 0, 0);
    // cross term: w2x[w] = sum_r a[w][r] * Y[r][w] (register-local dot)
    float p = 0.f;
#pragma unroll
    for (int nt = 0; nt < 3; ++nt)
#pragma unroll
      for (int rg = 0; rg < 4; ++rg)
        p += a_all[mt][nt][rg] * Yt[nt][rg];
    p *= inv4[mt];   // a_all holds un-normalized e
    p += __shfl_xor(p, 16); p += __shfl_xor(p, 32);
    if (quad == 0) lds.w2x[wv][mt * 16 + l15] = p;
  }

  // final: lane = word
  float simv = 0.f;
  if (lane < clen) {
    const float w2sq = fmaxf(lds.w2x[wv][lane] + lds.w2d[wv][lane], 0.f);
    const float w2v = sqrtf(w2sq);
    const float w12v = lds.w12[wv][lane];
    const float w1v = w1[(size_t)c * WPAD + lane];
    simv = w12v / fmaxf(w1v * w2v, 1e-8f);
  }
  simv += __shfl_xor(simv, 1);
  simv += __shfl_xor(simv, 2);
  simv += __shfl_xor(simv, 4);
  simv += __shfl_xor(simv, 8);
  simv += __shfl_xor(simv, 16);
  simv += __shfl_xor(simv, 32);
  if (lane == 0) out[(size_t)img * NCAP + c] = simv / (float)clen;
}

extern "C" void kernel_launch(void* const* d_in, const int* in_sizes, int n_in,
                              void* d_out, int out_size, void* d_ws, size_t ws_size,
                              hipStream_t stream) {
  const float* imgs = (const float*)d_in[0];
  const float* caps = (const float*)d_in[1];
  const int* cap_lens = (const int*)d_in[3];   // img_lens (d_in[2]) unused by reference
  float* out = (float*)d_out;

  char* ws = (char*)d_ws;
  const size_t QBF_B = (size_t)NCAP * 32 * 4 * 512 * 2;      // 33,554,432
  const size_t IBF_B = (size_t)NIMG * 32 * 3 * 512 * 2;      // 25,165,824
  const size_t W1_B = (size_t)NCAP * WPAD * 4;               // 65,536
  const size_t GBF_B = (size_t)NIMG * 48 * 64 * 2;           // 1,572,864
  unsigned short* qbfF = (unsigned short*)ws;
  unsigned short* ibfF = (unsigned short*)(ws + QBF_B);
  float* w1 = (float*)(ws + QBF_B + IBF_B);
  unsigned short* gbf = (unsigned short*)(ws + QBF_B + IBF_B + W1_B);
  float* gdiag = (float*)(ws + QBF_B + IBF_B + W1_B + GBF_B);

  k_prep_w1<<<NCAP * WPAD, 256, 0, stream>>>(caps, cap_lens, w1);
  k_prep_caps_frag<<<dim3(32, NCAP), 256, 0, stream>>>(caps, cap_lens, qbfF);
  k_prep_imgs_frag<<<dim3(32, NIMG), 192, 0, stream>>>(imgs, ibfF);
  k_gram_mfma<<<NIMG, 64, 0, stream>>>(imgs, ibfF, gbf, gdiag);
  k_main<<<dim3(NIMG / 2, NCAP / 2), 256, 0, stream>>>(qbfF, ibfF, w1, gbf, gdiag, cap_lens, out);
}